// Round 2
// baseline (6741891.406 us; speedup 1.0000x reference)
//
#include <hip/hip_runtime.h>
#include <stdint.h>

using u16 = unsigned short;
using u32 = unsigned int;
using u64 = unsigned long long;

typedef short bf8_t __attribute__((ext_vector_type(8)));   // 8 bf16 values (4 VGPRs)
typedef float f4_t  __attribute__((ext_vector_type(4)));

// ---------- helpers ----------
__device__ __forceinline__ u16 f2bf(float f) {
  u32 u = __float_as_uint(f);
  u32 r = (u + 0x7FFFu + ((u >> 16) & 1u)) >> 16;   // RNE
  return (u16)r;
}

__device__ __forceinline__ void cp16(const void* g, void* l) {
  // async global->LDS, 16B per lane; LDS dest = wave-uniform base + lane*16
  __builtin_amdgcn_global_load_lds(
      (const __attribute__((address_space(1))) u32*)g,
      (__attribute__((address_space(3))) u32*)l, 16, 0, 0);
}

// JAX threefry2x32, key = (0, 42)  [jax.random.key(42)]
__device__ __forceinline__ void threefry_0_42(u32 x0, u32 x1, u32& o0, u32& o1) {
  const u32 k0 = 0u, k1 = 42u;
  const u32 k2 = 0x1BD11BDAu ^ k0 ^ k1;
#define TFR(r) { x0 += x1; x1 = (x1 << r) | (x1 >> (32 - r)); x1 ^= x0; }
  x0 += k0; x1 += k1;
  TFR(13) TFR(15) TFR(26) TFR(6)   x0 += k1; x1 += k2 + 1u;
  TFR(17) TFR(29) TFR(16) TFR(24)  x0 += k2; x1 += k0 + 2u;
  TFR(13) TFR(15) TFR(26) TFR(6)   x0 += k0; x1 += k1 + 3u;
  TFR(17) TFR(29) TFR(16) TFR(24)  x0 += k1; x1 += k2 + 4u;
  TFR(13) TFR(15) TFR(26) TFR(6)   x0 += k2; x1 += k0 + 5u;
#undef TFR
  o0 = x0; o1 = x1;
}

// ---------- conversion / padding ----------
__global__ __launch_bounds__(256)
void cvt_bf16(const float* __restrict__ s, u16* __restrict__ d, int n4) {
  const int i = blockIdx.x * 256 + threadIdx.x;
  if (i >= n4) return;
  const float4 v = ((const float4*)s)[i];
  ushort4 o;
  o.x = f2bf(v.x); o.y = f2bf(v.y); o.z = f2bf(v.z); o.w = f2bf(v.w);
  ((ushort4*)d)[i] = o;
}

__global__ __launch_bounds__(256)
void pad_cls(const float* __restrict__ src, u16* __restrict__ dst) {
  const int i = blockIdx.x * 256 + threadIdx.x;      // 32*2048
  const int row = i >> 11, col = i & 2047;
  dst[i] = (row < 21) ? f2bf(src[row * 2048 + col]) : (u16)0;
}

__global__ __launch_bounds__(256)
void pad_head(const float* __restrict__ cf, const float* __restrict__ mk,
              u16* __restrict__ dst) {
  const int i = blockIdx.x * 256 + threadIdx.x;      // 32*1024
  const int row = i >> 10, col = i & 1023;
  float v = 0.0f;
  if (row < 22)      v = cf[row * 1024 + col];
  else if (row < 24) v = mk[(row - 22) * 1024 + col];
  dst[i] = f2bf(v);
}

// zero flags (8 groups x 32 slots x 16 u32 = 4096) + 8 slot counters at [4096..4103].
// ws is re-poisoned before every timed launch -> must re-init every call.
__global__ __launch_bounds__(256)
void init_flags(u32* __restrict__ flags) {
  const int i = blockIdx.x * 256 + threadIdx.x;      // 17*256 = 4352 u32
  flags[i] = 0u;
}

// ---------- big GEMM: C[M,N] = A[M,K] * B[N,K]^T (+bias, opt relu) ----------
// 128x128 tile, BK=64, 256 threads (4 waves as 2x2 of 64x64)
template<int RELU>
__global__ __launch_bounds__(256)
void gemm128(const u16* __restrict__ A, const u16* __restrict__ Bw,
             const float* __restrict__ bias, float* __restrict__ C,
             int N, int K) {
  __shared__ __align__(16) u16 As[128 * 64];
  __shared__ __align__(16) u16 Bs[128 * 64];
  const int tid = threadIdx.x;
  const int wv = tid >> 6, lane = tid & 63;
  const int wm = wv >> 1, wn = wv & 1;
  const u16* Ab = A + (size_t)blockIdx.x * 128 * K;
  const u16* Bb = Bw + (size_t)blockIdx.y * 128 * K;
  const int lr = lane >> 3, lc = lane & 7;
  f4_t acc[4][4] = {};
  for (int k0 = 0; k0 < K; k0 += 64) {
#pragma unroll
    for (int i = 0; i < 4; ++i) {
      const int row = wv * 32 + i * 8;
      cp16(Ab + (size_t)(row + lr) * K + (k0 + lc * 8), &As[row * 64]);
      cp16(Bb + (size_t)(row + lr) * K + (k0 + lc * 8), &Bs[row * 64]);
    }
    __syncthreads();
#pragma unroll
    for (int kk = 0; kk < 2; ++kk) {
      bf8_t av[4], bv[4];
#pragma unroll
      for (int mt = 0; mt < 4; ++mt)
        av[mt] = *(const bf8_t*)&As[(wm * 64 + mt * 16 + (lane & 15)) * 64 + kk * 32 + (lane >> 4) * 8];
#pragma unroll
      for (int nt = 0; nt < 4; ++nt)
        bv[nt] = *(const bf8_t*)&Bs[(wn * 64 + nt * 16 + (lane & 15)) * 64 + kk * 32 + (lane >> 4) * 8];
#pragma unroll
      for (int mt = 0; mt < 4; ++mt)
#pragma unroll
        for (int nt = 0; nt < 4; ++nt)
          acc[mt][nt] = __builtin_amdgcn_mfma_f32_16x16x32_bf16(av[mt], bv[nt], acc[mt][nt], 0, 0, 0);
    }
    __syncthreads();
  }
  const int q = lane >> 4, cn = lane & 15;
#pragma unroll
  for (int mt = 0; mt < 4; ++mt) {
#pragma unroll
    for (int nt = 0; nt < 4; ++nt) {
      const int col = blockIdx.y * 128 + wn * 64 + nt * 16 + cn;
      const float bb = bias[col];
#pragma unroll
      for (int r = 0; r < 4; ++r) {
        const int row = blockIdx.x * 128 + wm * 64 + mt * 16 + q * 4 + r;
        float v = acc[mt][nt][r] + bb;
        if (RELU) v = fmaxf(v, 0.0f);
        C[(size_t)row * N + col] = v;
      }
    }
  }
}

// ---------- skinny GEMM: C[M,32] = A[M,K] * B[32,K]^T, M-tile 64 ----------
// HEAD=0: vl_preds (cols<21, +cls_b). HEAD=1: enc (cols<22,+cf_b) / mask (cols 22..23,+mk_b)
template<int HEAD>
__global__ __launch_bounds__(256)
void gemm_skinny(const u16* __restrict__ A, const u16* __restrict__ Bw,
                 const float* __restrict__ bias, const float* __restrict__ bias2,
                 float* __restrict__ C0, float* __restrict__ C1, int K) {
  __shared__ __align__(16) u16 As[64 * 64];
  __shared__ __align__(16) u16 Bs[32 * 64];
  const int tid = threadIdx.x, wv = tid >> 6, lane = tid & 63;
  const u16* Ab = A + (size_t)blockIdx.x * 64 * K;
  const int lr = lane >> 3, lc = lane & 7;
  f4_t acc[2] = {};
  for (int k0 = 0; k0 < K; k0 += 64) {
#pragma unroll
    for (int i = 0; i < 2; ++i) {
      const int row = wv * 16 + i * 8;
      cp16(Ab + (size_t)(row + lr) * K + (k0 + lc * 8), &As[row * 64]);
    }
    {
      const int row = wv * 8;
      cp16(Bw + (size_t)(row + lr) * K + (k0 + lc * 8), &Bs[row * 64]);
    }
    __syncthreads();
#pragma unroll
    for (int kk = 0; kk < 2; ++kk) {
      bf8_t a = *(const bf8_t*)&As[(wv * 16 + (lane & 15)) * 64 + kk * 32 + (lane >> 4) * 8];
#pragma unroll
      for (int nt = 0; nt < 2; ++nt) {
        bf8_t b = *(const bf8_t*)&Bs[(nt * 16 + (lane & 15)) * 64 + kk * 32 + (lane >> 4) * 8];
        acc[nt] = __builtin_amdgcn_mfma_f32_16x16x32_bf16(a, b, acc[nt], 0, 0, 0);
      }
    }
    __syncthreads();
  }
  const int q = lane >> 4, cn = lane & 15;
#pragma unroll
  for (int nt = 0; nt < 2; ++nt) {
    const int col = nt * 16 + cn;
#pragma unroll
    for (int r = 0; r < 4; ++r) {
      const int row = blockIdx.x * 64 + wv * 16 + q * 4 + r;
      const float v = acc[nt][r];
      if (HEAD) {
        if (col < 22)      C0[(size_t)row * 22 + col] = v + bias[col];
        else if (col < 24) C1[(size_t)row * 2 + (col - 22)] = v + bias2[col - 22];
      } else {
        if (col < 21)      C0[(size_t)row * 21 + col] = v + bias[col];
      }
    }
  }
}

// ---------- dropout: JAX partitionable threefry bernoulli, key 42, p_keep=0.7 ----------
__global__ __launch_bounds__(256)
void dropout_kernel(float* __restrict__ x, u16* __restrict__ xbf) {
  const u32 tid = blockIdx.x * 256u + threadIdx.x;   // 2^22 threads
  const u32 j0 = tid * 4u;
  float4 a = *(const float4*)(x + j0);
  float av[4] = {a.x, a.y, a.z, a.w};
  u16 abf[4];
#pragma unroll
  for (int i = 0; i < 4; ++i) {
    u32 o0, o1;
    threefry_0_42(0u, j0 + (u32)i, o0, o1);
    const u32 bits = o0 ^ o1;
    const float u1 = __uint_as_float((bits >> 9) | 0x3f800000u) - 1.0f;
    av[i] = (u1 < 0.7f) ? av[i] * (1.0f / 0.7f) : 0.0f;
    abf[i] = f2bf(av[i]);
  }
  float4 oa; oa.x = av[0]; oa.y = av[1]; oa.z = av[2]; oa.w = av[3];
  *(float4*)(x + j0) = oa;
  ushort4 ua; ua.x = abf[0]; ua.y = abf[1]; ua.z = abf[2]; ua.w = abf[3];
  *(ushort4*)(xbf + j0) = ua;
}

// ---------- persistent GRU v4: XCD-local groups, L2-coherent sync ----------
// 256 blocks x 256 threads, 1 block/CU forced via LDS > 80 KB => pigeonhole puts
// exactly 32 blocks on each of the 8 XCDs. Each block reads its physical XCD id
// (HW_REG_XCC_ID) and self-assigns: group = xcd (16 seqs), slot = atomicAdd ->
// 32-col slice. All cross-block h/flag traffic stays inside the XCD's private
// L2: plain stores (vector L1 is write-through -> lands in L2) + sc0 loads
// (bypass L1, served by L2). No sc1/LLC round-trips in the step loop.
// [R6 theory: prior 6.3 us/step was ~3-4 serial LLC RTs; L2 RT is ~10x cheaper.]
// Correctness does NOT depend on dispatch order: grouping is derived from actual
// placement; co-residency (already required for polling) + 1 block/CU gives
// exactly 32 blocks/XCD. Weights (96 rows x K-slice 256) live in 192 VGPRs/lane.
// Ordering per step: plain h stores -> s_waitcnt vmcnt(0) (per wave) ->
// __syncthreads -> tid0 stores flag (plain) -> wave0 lanes 0..31 poll the 32
// group flags with sc0 loads; hrbf store + gi prefetch overlap the poll.
#define GRU_BLOCKS 256
__global__ __launch_bounds__(256, 1)
void gru_persistent(const u16* __restrict__ whh, const float* __restrict__ gi,
                    const float* __restrict__ bhh, u16* __restrict__ hbuf0,
                    u16* __restrict__ hbuf1, u16* __restrict__ hrbf,
                    u32* flags) {
  __shared__ __align__(16) float Gs[4][16 * 100];     // 25.6 KB wave-partial G
  __shared__ u32 slot_sh;
  __shared__ __align__(16) u32 ldspad[14848];         // 59.4 KB pad -> 85 KB total => 1 block/CU
  asm volatile("" :: "v"((u32)(size_t)(void*)ldspad) : "memory");  // keep pad allocated

  const int tid = threadIdx.x, wv = tid >> 6, lane = tid & 63;
  const int la15 = lane & 15, la16 = lane >> 4;

  // ---- self-organize by physical XCD ----
  u32 xcc;
  asm("s_getreg_b32 %0, hwreg(HW_REG_XCC_ID)" : "=s"(xcc));
  xcc &= 7u;
  if (tid == 0) slot_sh = atomicAdd(&flags[4096 + xcc], 1u) & 31u;  // device-scope
  __syncthreads();
  const int slot = (int)slot_sh;
  const int col0 = slot * 32;                          // 32 hid cols per block
  const int seq0 = (int)xcc * 16;                      // 16 seqs per group
  u32* const grp_flags = flags + xcc * 512;            // 32 flags, 64 B apart
  u32* const my_flag = grp_flags + slot * 16;

  // ---- whh slab in registers: 96 rows (r,z,n x 32 cols) x this wave's K=256 ----
  const int kb = wv * 256 + la16 * 8;                  // this wave's K slice base
  bf8_t Breg[6][8];                                    // 192 VGPRs, loop-invariant
#pragma unroll
  for (int nt = 0; nt < 6; ++nt) {
    const size_t grow = (size_t)((nt >> 1) * 1024 + col0 + (nt & 1) * 16 + la15);
#pragma unroll
    for (int kc = 0; kc < 8; ++kc)
      Breg[nt][kc] = *(const bf8_t*)&whh[grow * 1024 + kb + kc * 32];
  }

  // ---- per-thread persistent state: 1 seq x 2 adjacent cols ----
  const int j2 = (tid & 15) * 2;                       // even col within 32-tile
  const int m = tid >> 4;                              // seq within group (0..15)
  const int colA = col0 + j2;
  const int seq = seq0 + m;
  float h0 = 0.0f, h1 = 0.0f;                          // fp32 h master copy (regs)
  const float2 bR = *(const float2*)(bhh + colA);
  const float2 bZ = *(const float2*)(bhh + 1024 + colA);
  const float2 bN = *(const float2*)(bhh + 2048 + colA);
  const size_t gb0 = ((size_t)((seq >> 3) * 512 + (seq & 7) * 64)) * 3072 + colA;
  float2 giR = *(const float2*)(gi + gb0);
  float2 giZ = *(const float2*)(gi + gb0 + 1024);
  float2 giN = *(const float2*)(gi + gb0 + 2048);

  // A-fragment read bases (per-lane row seq0+la15, this wave's K slice)
  const u16* const hA0 = hbuf0 + (size_t)(seq0 + la15) * 1024 + kb;
  const u16* const hA1 = hbuf1 + (size_t)(seq0 + la15) * 1024 + kb;

  for (int t = 0; t < 64; ++t) {
    float Gr0 = 0.f, Gr1 = 0.f, Gz0 = 0.f, Gz1 = 0.f, Gn0 = 0.f, Gn1 = 0.f;
    if (t > 0) {
      const u16* hr = (t & 1) ? hA1 : hA0;
      // ---- h fragments: sc0 loads (L1-bypass, served by this XCD's L2) ----
      bf8_t a[8];
#pragma unroll
      for (int kc = 0; kc < 8; ++kc)
        asm volatile("global_load_dwordx4 %0, %1, off sc0"
                     : "=v"(a[kc]) : "v"(hr + kc * 32));
      asm volatile("s_waitcnt vmcnt(0)" ::: "memory");
      __builtin_amdgcn_sched_barrier(0);               // rule #18: pin MFMAs after wait
      // ---- G partial = h[16 x K-slice] @ Ws^T (weights from registers) ----
      f4_t acc[6] = {};
#pragma unroll
      for (int kc = 0; kc < 8; ++kc)
#pragma unroll
        for (int nt = 0; nt < 6; ++nt)
          acc[nt] = __builtin_amdgcn_mfma_f32_16x16x32_bf16(a[kc], Breg[nt][kc], acc[nt], 0, 0, 0);
      // ---- stash partials (C layout: col=lane&15, row=quad*4+r) ----
#pragma unroll
      for (int nt = 0; nt < 6; ++nt)
#pragma unroll
        for (int r = 0; r < 4; ++r)
          Gs[wv][(la16 * 4 + r) * 100 + nt * 16 + la15] = acc[nt][r];
      __syncthreads();
      // ---- reduce 4 wave-partials (float2 per gate) ----
#pragma unroll
      for (int w = 0; w < 4; ++w) {
        const float2 r2 = *(const float2*)&Gs[w][m * 100 + j2];
        const float2 z2 = *(const float2*)&Gs[w][m * 100 + 32 + j2];
        const float2 n2 = *(const float2*)&Gs[w][m * 100 + 64 + j2];
        Gr0 += r2.x; Gr1 += r2.y; Gz0 += z2.x; Gz1 += z2.y; Gn0 += n2.x; Gn1 += n2.y;
      }
    }
    // ---- gate math (2 cols) ----
    const float gr0 = Gr0 + bR.x + giR.x, gr1 = Gr1 + bR.y + giR.y;
    const float gz0 = Gz0 + bZ.x + giZ.x, gz1 = Gz1 + bZ.y + giZ.y;
    const float gh0 = Gn0 + bN.x,         gh1 = Gn1 + bN.y;   // b_hh on n-gate scaled by r
    const float rr0 = 1.0f / (1.0f + __expf(-gr0)), rr1 = 1.0f / (1.0f + __expf(-gr1));
    const float zz0 = 1.0f / (1.0f + __expf(-gz0)), zz1 = 1.0f / (1.0f + __expf(-gz1));
    float tg0 = giN.x + rr0 * gh0, tg1 = giN.y + rr1 * gh1;
    tg0 = fminf(fmaxf(tg0, -15.0f), 15.0f);
    tg1 = fminf(fmaxf(tg1, -15.0f), 15.0f);
    const float e20 = __expf(2.0f * tg0), e21 = __expf(2.0f * tg1);
    const float nn0 = (e20 - 1.0f) / (e20 + 1.0f), nn1 = (e21 - 1.0f) / (e21 + 1.0f);
    h0 = (1.0f - zz0) * nn0 + zz0 * h0;
    h1 = (1.0f - zz1) * nn1 + zz1 * h1;
    const u32 hrpack = (u32)f2bf(fmaxf(h0, 0.0f)) | ((u32)f2bf(fmaxf(h1, 0.0f)) << 16);
    if (t < 63) {
      // ---- h store: plain (write-through L1 -> lands in this XCD's L2) ----
      u16* hw = (t & 1) ? hbuf0 : hbuf1;
      const u32 hpack = (u32)f2bf(h0) | ((u32)f2bf(h1) << 16);
      __hip_atomic_store((u32*)(hw + (size_t)seq * 1024 + colA), hpack,
                         __ATOMIC_RELAXED, __HIP_MEMORY_SCOPE_WORKGROUP);
      // ---- arrival: drain this wave's stores into L2, block-sync, store flag ----
      asm volatile("s_waitcnt vmcnt(0)" ::: "memory");
      __syncthreads();
      if (tid == 0)
        __hip_atomic_store(my_flag, (u32)(t + 1), __ATOMIC_RELAXED,
                           __HIP_MEMORY_SCOPE_WORKGROUP);
    }
    // ---- hrbf store + gi prefetch overlap the poll window ----
    *(u32*)(hrbf + ((size_t)t * 128 + seq) * 1024 + colA) = hrpack;
    if (t < 63) {
      const size_t g = gb0 + (size_t)(t + 1) * 3072;
      giR = *(const float2*)(gi + g);
      giZ = *(const float2*)(gi + g + 1024);
      giN = *(const float2*)(gi + g + 2048);
      // ---- wave0 lanes 0..31 poll the 32 group flags (sc0 = fresh from L2) ----
      if (wv == 0) {
        const u32 target = (u32)(t + 1);
        u32* const fl = grp_flags + lane * 16;
        int guard = 0;
        while (true) {
          u32 v = target;
          if (lane < 32)
            asm volatile("global_load_dword %0, %1, off sc0\n\ts_waitcnt vmcnt(0)"
                         : "=v"(v) : "v"(fl) : "memory");
          if (__ballot(v >= target) == ~0ull) break;
          if (++guard > 1000000) break;                // fail-fast, never hang
        }
      }
      __syncthreads();
    }
  }
}

// ---------- host ----------
extern "C" void kernel_launch(void* const* d_in, const int* in_sizes, int n_in,
                              void* d_out, int out_size, void* d_ws, size_t ws_size,
                              hipStream_t stream) {
  const float* feats = (const float*)d_in[0];
  const float* fc_w  = (const float*)d_in[1];
  const float* fc_b  = (const float*)d_in[2];
  const float* cls_w = (const float*)d_in[3];
  const float* cls_b = (const float*)d_in[4];
  const float* w_ih  = (const float*)d_in[5];
  const float* w_hh  = (const float*)d_in[6];
  const float* b_ih  = (const float*)d_in[7];
  const float* b_hh  = (const float*)d_in[8];
  const float* cf_w  = (const float*)d_in[9];
  const float* cf_b  = (const float*)d_in[10];
  const float* mk_w  = (const float*)d_in[11];
  const float* mk_b  = (const float*)d_in[12];

  char* ws = (char*)d_ws;
  size_t off = 0;
  auto alloc = [&](size_t b) { char* p = ws + off; off += (b + 255) & ~(size_t)255; return p; };
  u16*  featsbf = (u16*)alloc((size_t)8192 * 2048 * 2);
  u16*  xbf     = featsbf;                 // alias: feats_bf dead after fc GEMM
  u16*  fcwbf   = (u16*)alloc((size_t)2048 * 2048 * 2);
  u16*  wihbf   = (u16*)alloc((size_t)3072 * 2048 * 2);
  u16*  whhbf   = (u16*)alloc((size_t)3072 * 1024 * 2);
  u16*  clsp    = (u16*)alloc((size_t)32 * 2048 * 2);
  u16*  headp   = (u16*)alloc((size_t)32 * 1024 * 2);
  float* gi     = (float*)alloc((size_t)8192 * 3072 * 4);
  u16*  hbf0    = (u16*)alloc((size_t)128 * 1024 * 2);
  u16*  hbf1    = (u16*)alloc((size_t)128 * 1024 * 2);
  u16*  hrbf    = (u16*)alloc((size_t)8192 * 1024 * 2);
  u32*  flags   = (u32*)alloc(4352 * 4);   // 8 groups x 32 flag lines + 8 counters

  float* out_enc  = (float*)d_out;                       // [8192,22]
  float* out_mask = out_enc + (size_t)8192 * 22;         // [8192,2]
  float* out_x    = out_mask + (size_t)8192 * 2;         // [16,512,2048]
  float* out_vl   = out_x + (size_t)8192 * 2048;         // [16,512,21]

  cvt_bf16<<<16384, 256, 0, stream>>>(feats, featsbf, 4194304);
  cvt_bf16<<<4096, 256, 0, stream>>>(fc_w, fcwbf, 1048576);
  cvt_bf16<<<6144, 256, 0, stream>>>(w_ih, wihbf, 1572864);
  cvt_bf16<<<3072, 256, 0, stream>>>(w_hh, whhbf, 786432);
  pad_cls<<<256, 256, 0, stream>>>(cls_w, clsp);
  pad_head<<<128, 256, 0, stream>>>(cf_w, mk_w, headp);
  init_flags<<<17, 256, 0, stream>>>(flags);

  // x_pre = relu(feats @ fc_w^T + fc_b) -> out_x (fp32)
  gemm128<1><<<dim3(64, 16), 256, 0, stream>>>(featsbf, fcwbf, fc_b, out_x, 2048, 2048);
  // in-place dropout on out_x; also writes bf16 x into ws
  dropout_kernel<<<16384, 256, 0, stream>>>(out_x, xbf);
  // vl_preds
  gemm_skinny<0><<<128, 256, 0, stream>>>(xbf, clsp, cls_b, nullptr, out_vl, nullptr, 2048);
  // gi = x @ w_ih^T + b_ih   (b_hh NOT folded: n-gate needs r*(gh+b_hh))
  gemm128<0><<<dim3(64, 24), 256, 0, stream>>>(xbf, wihbf, b_ih, gi, 3072, 2048);

  // all 64 GRU steps in one persistent kernel (8 XCD-local 32-block groups)
  gru_persistent<<<GRU_BLOCKS, 256, 0, stream>>>(whhbf, gi, b_hh, hbf0, hbf1, hrbf, flags);

  // heads: enc_scores + mask_scores
  gemm_skinny<1><<<128, 256, 0, stream>>>(hrbf, headp, cf_b, mk_b, out_enc, out_mask, 1024);
}

// Round 3
// 947.514 us; speedup vs baseline: 7115.3464x; 7115.3464x over previous
//
#include <hip/hip_runtime.h>
#include <stdint.h>

using u16 = unsigned short;
using u32 = unsigned int;
using u64 = unsigned long long;

typedef short bf8_t __attribute__((ext_vector_type(8)));   // 8 bf16 values (4 VGPRs)
typedef float f4_t  __attribute__((ext_vector_type(4)));

// ---------- helpers ----------
__device__ __forceinline__ u16 f2bf(float f) {
  u32 u = __float_as_uint(f);
  u32 r = (u + 0x7FFFu + ((u >> 16) & 1u)) >> 16;   // RNE
  return (u16)r;
}

__device__ __forceinline__ void cp16(const void* g, void* l) {
  // async global->LDS, 16B per lane; LDS dest = wave-uniform base + lane*16
  __builtin_amdgcn_global_load_lds(
      (const __attribute__((address_space(1))) u32*)g,
      (__attribute__((address_space(3))) u32*)l, 16, 0, 0);
}

// JAX threefry2x32, key = (0, 42)  [jax.random.key(42)]
__device__ __forceinline__ void threefry_0_42(u32 x0, u32 x1, u32& o0, u32& o1) {
  const u32 k0 = 0u, k1 = 42u;
  const u32 k2 = 0x1BD11BDAu ^ k0 ^ k1;
#define TFR(r) { x0 += x1; x1 = (x1 << r) | (x1 >> (32 - r)); x1 ^= x0; }
  x0 += k0; x1 += k1;
  TFR(13) TFR(15) TFR(26) TFR(6)   x0 += k1; x1 += k2 + 1u;
  TFR(17) TFR(29) TFR(16) TFR(24)  x0 += k2; x1 += k0 + 2u;
  TFR(13) TFR(15) TFR(26) TFR(6)   x0 += k0; x1 += k1 + 3u;
  TFR(17) TFR(29) TFR(16) TFR(24)  x0 += k1; x1 += k2 + 4u;
  TFR(13) TFR(15) TFR(26) TFR(6)   x0 += k2; x1 += k0 + 5u;
#undef TFR
  o0 = x0; o1 = x1;
}

// ---------- conversion / padding ----------
__global__ __launch_bounds__(256)
void cvt_bf16(const float* __restrict__ s, u16* __restrict__ d, int n4) {
  const int i = blockIdx.x * 256 + threadIdx.x;
  if (i >= n4) return;
  const float4 v = ((const float4*)s)[i];
  ushort4 o;
  o.x = f2bf(v.x); o.y = f2bf(v.y); o.z = f2bf(v.z); o.w = f2bf(v.w);
  ((ushort4*)d)[i] = o;
}

__global__ __launch_bounds__(256)
void pad_cls(const float* __restrict__ src, u16* __restrict__ dst) {
  const int i = blockIdx.x * 256 + threadIdx.x;      // 32*2048
  const int row = i >> 11, col = i & 2047;
  dst[i] = (row < 21) ? f2bf(src[row * 2048 + col]) : (u16)0;
}

__global__ __launch_bounds__(256)
void pad_head(const float* __restrict__ cf, const float* __restrict__ mk,
              u16* __restrict__ dst) {
  const int i = blockIdx.x * 256 + threadIdx.x;      // 32*1024
  const int row = i >> 10, col = i & 1023;
  float v = 0.0f;
  if (row < 22)      v = cf[row * 1024 + col];
  else if (row < 24) v = mk[(row - 22) * 1024 + col];
  dst[i] = f2bf(v);
}

// ---------- big GEMM: C[M,N] = A[M,K] * B[N,K]^T (+bias, opt relu) ----------
// 128x128 tile, BK=64, 256 threads (4 waves as 2x2 of 64x64)
template<int RELU>
__global__ __launch_bounds__(256)
void gemm128(const u16* __restrict__ A, const u16* __restrict__ Bw,
             const float* __restrict__ bias, float* __restrict__ C,
             int N, int K) {
  __shared__ __align__(16) u16 As[128 * 64];
  __shared__ __align__(16) u16 Bs[128 * 64];
  const int tid = threadIdx.x;
  const int wv = tid >> 6, lane = tid & 63;
  const int wm = wv >> 1, wn = wv & 1;
  const u16* Ab = A + (size_t)blockIdx.x * 128 * K;
  const u16* Bb = Bw + (size_t)blockIdx.y * 128 * K;
  const int lr = lane >> 3, lc = lane & 7;
  f4_t acc[4][4] = {};
  for (int k0 = 0; k0 < K; k0 += 64) {
#pragma unroll
    for (int i = 0; i < 4; ++i) {
      const int row = wv * 32 + i * 8;
      cp16(Ab + (size_t)(row + lr) * K + (k0 + lc * 8), &As[row * 64]);
      cp16(Bb + (size_t)(row + lr) * K + (k0 + lc * 8), &Bs[row * 64]);
    }
    __syncthreads();
#pragma unroll
    for (int kk = 0; kk < 2; ++kk) {
      bf8_t av[4], bv[4];
#pragma unroll
      for (int mt = 0; mt < 4; ++mt)
        av[mt] = *(const bf8_t*)&As[(wm * 64 + mt * 16 + (lane & 15)) * 64 + kk * 32 + (lane >> 4) * 8];
#pragma unroll
      for (int nt = 0; nt < 4; ++nt)
        bv[nt] = *(const bf8_t*)&Bs[(wn * 64 + nt * 16 + (lane & 15)) * 64 + kk * 32 + (lane >> 4) * 8];
#pragma unroll
      for (int mt = 0; mt < 4; ++mt)
#pragma unroll
        for (int nt = 0; nt < 4; ++nt)
          acc[mt][nt] = __builtin_amdgcn_mfma_f32_16x16x32_bf16(av[mt], bv[nt], acc[mt][nt], 0, 0, 0);
    }
    __syncthreads();
  }
  const int q = lane >> 4, cn = lane & 15;
#pragma unroll
  for (int mt = 0; mt < 4; ++mt) {
#pragma unroll
    for (int nt = 0; nt < 4; ++nt) {
      const int col = blockIdx.y * 128 + wn * 64 + nt * 16 + cn;
      const float bb = bias[col];
#pragma unroll
      for (int r = 0; r < 4; ++r) {
        const int row = blockIdx.x * 128 + wm * 64 + mt * 16 + q * 4 + r;
        float v = acc[mt][nt][r] + bb;
        if (RELU) v = fmaxf(v, 0.0f);
        C[(size_t)row * N + col] = v;
      }
    }
  }
}

// ---------- skinny GEMM: C[M,32] = A[M,K] * B[32,K]^T, M-tile 64 ----------
// HEAD=0: vl_preds (cols<21, +cls_b). HEAD=1: enc (cols<22,+cf_b) / mask (cols 22..23,+mk_b)
template<int HEAD>
__global__ __launch_bounds__(256)
void gemm_skinny(const u16* __restrict__ A, const u16* __restrict__ Bw,
                 const float* __restrict__ bias, const float* __restrict__ bias2,
                 float* __restrict__ C0, float* __restrict__ C1, int K) {
  __shared__ __align__(16) u16 As[64 * 64];
  __shared__ __align__(16) u16 Bs[32 * 64];
  const int tid = threadIdx.x, wv = tid >> 6, lane = tid & 63;
  const u16* Ab = A + (size_t)blockIdx.x * 64 * K;
  const int lr = lane >> 3, lc = lane & 7;
  f4_t acc[2] = {};
  for (int k0 = 0; k0 < K; k0 += 64) {
#pragma unroll
    for (int i = 0; i < 2; ++i) {
      const int row = wv * 16 + i * 8;
      cp16(Ab + (size_t)(row + lr) * K + (k0 + lc * 8), &As[row * 64]);
    }
    {
      const int row = wv * 8;
      cp16(Bw + (size_t)(row + lr) * K + (k0 + lc * 8), &Bs[row * 64]);
    }
    __syncthreads();
#pragma unroll
    for (int kk = 0; kk < 2; ++kk) {
      bf8_t a = *(const bf8_t*)&As[(wv * 16 + (lane & 15)) * 64 + kk * 32 + (lane >> 4) * 8];
#pragma unroll
      for (int nt = 0; nt < 2; ++nt) {
        bf8_t b = *(const bf8_t*)&Bs[(nt * 16 + (lane & 15)) * 64 + kk * 32 + (lane >> 4) * 8];
        acc[nt] = __builtin_amdgcn_mfma_f32_16x16x32_bf16(a, b, acc[nt], 0, 0, 0);
      }
    }
    __syncthreads();
  }
  const int q = lane >> 4, cn = lane & 15;
#pragma unroll
  for (int nt = 0; nt < 2; ++nt) {
    const int col = nt * 16 + cn;
#pragma unroll
    for (int r = 0; r < 4; ++r) {
      const int row = blockIdx.x * 64 + wv * 16 + q * 4 + r;
      const float v = acc[nt][r];
      if (HEAD) {
        if (col < 22)      C0[(size_t)row * 22 + col] = v + bias[col];
        else if (col < 24) C1[(size_t)row * 2 + (col - 22)] = v + bias2[col - 22];
      } else {
        if (col < 21)      C0[(size_t)row * 21 + col] = v + bias[col];
      }
    }
  }
}

// ---------- dropout: JAX partitionable threefry bernoulli, key 42, p_keep=0.7 ----------
__global__ __launch_bounds__(256)
void dropout_kernel(float* __restrict__ x, u16* __restrict__ xbf) {
  const u32 tid = blockIdx.x * 256u + threadIdx.x;   // 2^22 threads
  const u32 j0 = tid * 4u;
  float4 a = *(const float4*)(x + j0);
  float av[4] = {a.x, a.y, a.z, a.w};
  u16 abf[4];
#pragma unroll
  for (int i = 0; i < 4; ++i) {
    u32 o0, o1;
    threefry_0_42(0u, j0 + (u32)i, o0, o1);
    const u32 bits = o0 ^ o1;
    const float u1 = __uint_as_float((bits >> 9) | 0x3f800000u) - 1.0f;
    av[i] = (u1 < 0.7f) ? av[i] * (1.0f / 0.7f) : 0.0f;
    abf[i] = f2bf(av[i]);
  }
  float4 oa; oa.x = av[0]; oa.y = av[1]; oa.z = av[2]; oa.w = av[3];
  *(float4*)(x + j0) = oa;
  ushort4 ua; ua.x = abf[0]; ua.y = abf[1]; ua.z = abf[2]; ua.w = abf[3];
  *(ushort4*)(xbf + j0) = ua;
}

// ---------- persistent GRU v5: tagged-data sync (no flags, no ack wait) ----------
// 256 blocks x 256 threads, co-resident (1 block/CU via VGPR+LDS). Geometry:
// 8 groups (blockIdx>>5) x 16 seqs, 32 col-blocks (blockIdx&31) x 32 cols.
// h is exchanged as u64 {lo=2xbf16 hpack, hi=tag=t+1} agent-scope RELAXED
// atomics (sc1, LLC-coherent -- the ONLY proven cross-block visibility path;
// R2 post-mortem: plain-store->sc0-load timed out 104ms/step, 6.7s total).
// The tag makes each value self-validating: writers fire-and-forget (no vmcnt
// ack, no flag store, no end-of-step barrier); each reader wave polls its own
// 32 A-fragment u64s until all tags == t. Serial chain per step drops from
// ~4 LLC RTs (v3: store+ack, flag, poll, load = 6.3us/step) to ~2 (store
// propagate + poll detect). Two-buffer parity is race-free: reaching step s
// requires h(s-1) from all blocks, which requires they finished reading
// h(s-2) -- the only data step s overwrites. Poisoned 0xAA tags never equal
// targets 1..63, so no buffer init needed. Weights: 192 VGPRs/lane.
#define GRU_BLOCKS 256
__global__ __launch_bounds__(256, 1)
void gru_persistent(const u16* __restrict__ whh, const float* __restrict__ gi,
                    const float* __restrict__ bhh, u64* __restrict__ hbuf0,
                    u64* __restrict__ hbuf1, u16* __restrict__ hrbf) {
  __shared__ __align__(16) float Gs[4][16 * 100];     // 25.6 KB wave-partial G
  __shared__ __align__(16) u32 ldspad[14848];         // pad -> 85 KB => 1 block/CU
  asm volatile("" :: "v"((u32)(size_t)(void*)ldspad) : "memory");  // keep pad live

  const int tid = threadIdx.x, wv = tid >> 6, lane = tid & 63;
  const int la15 = lane & 15, la16 = lane >> 4;
  const int slot = blockIdx.x & 31, grp = blockIdx.x >> 5;
  const int col0 = slot * 32;                          // 32 hid cols per block
  const int seq0 = grp * 16;                           // 16 seqs per group

  // ---- whh slab in registers: 96 rows (r,z,n x 32 cols) x this wave's K=256 ----
  const int kb = wv * 256 + la16 * 8;                  // this wave's K slice base
  bf8_t Breg[6][8];                                    // 192 VGPRs, loop-invariant
#pragma unroll
  for (int nt = 0; nt < 6; ++nt) {
    const size_t grow = (size_t)((nt >> 1) * 1024 + col0 + (nt & 1) * 16 + la15);
#pragma unroll
    for (int kc = 0; kc < 8; ++kc)
      Breg[nt][kc] = *(const bf8_t*)&whh[grow * 1024 + kb + kc * 32];
  }

  // ---- per-thread persistent state: 1 seq x 2 adjacent cols ----
  const int j2 = (tid & 15) * 2;                       // even col within 32-tile
  const int m = tid >> 4;                              // seq within group (0..15)
  const int colA = col0 + j2;
  const int seq = seq0 + m;
  float h0 = 0.0f, h1 = 0.0f;                          // fp32 h master copy (regs)
  const float2 bR = *(const float2*)(bhh + colA);
  const float2 bZ = *(const float2*)(bhh + 1024 + colA);
  const float2 bN = *(const float2*)(bhh + 2048 + colA);
  const size_t gb0 = ((size_t)((seq >> 3) * 512 + (seq & 7) * 64)) * 3072 + colA;
  float2 giR = *(const float2*)(gi + gb0);
  float2 giZ = *(const float2*)(gi + gb0 + 1024);
  float2 giN = *(const float2*)(gi + gb0 + 2048);

  // reader fragment base (u64 units; row seq0+la15, this wave's K slice)
  const size_t rbase = (size_t)(seq0 + la15) * 512 + (size_t)(wv * 128 + la16 * 4);
  u64* const rA0 = hbuf0 + rbase;
  u64* const rA1 = hbuf1 + rbase;
  // writer address (u64 units)
  u64* const wA0 = hbuf0 + (size_t)seq * 512 + (colA >> 1);
  u64* const wA1 = hbuf1 + (size_t)seq * 512 + (colA >> 1);

  for (int t = 0; t < 64; ++t) {
    float Gr0 = 0.f, Gr1 = 0.f, Gz0 = 0.f, Gz1 = 0.f, Gn0 = 0.f, Gn1 = 0.f;
    if (t > 0) {
      u64* const rb = (t & 1) ? rA1 : rA0;             // buffer written at t-1
      const u32 target = (u32)t;
      u64 q[8][4];
      int guard = 0;
      while (true) {
        // 32 agent-scope u64 loads: 8 chunks (32-col stride) x 4 u64 (8 cols)
#pragma unroll
        for (int kc = 0; kc < 8; ++kc)
#pragma unroll
          for (int i = 0; i < 4; ++i)
            q[kc][i] = __hip_atomic_load(rb + kc * 16 + i,
                                         __ATOMIC_RELAXED, __HIP_MEMORY_SCOPE_AGENT);
        u32 ok = 1u;
#pragma unroll
        for (int kc = 0; kc < 8; ++kc)
#pragma unroll
          for (int i = 0; i < 4; ++i)
            ok &= (u32)((u32)(q[kc][i] >> 32) == target);
        if (__ballot(ok != 0u) == ~0ull) break;
        if (++guard > 50000) break;                    // fail-fast, never hang
      }
      // ---- G partial = h[16 x K-slice] @ Ws^T (weights from registers) ----
      f4_t acc[6] = {};
#pragma unroll
      for (int kc = 0; kc < 8; ++kc) {
        union { bf8_t v; u32 d[4]; } ua;
#pragma unroll
        for (int i = 0; i < 4; ++i) ua.d[i] = (u32)q[kc][i];
#pragma unroll
        for (int nt = 0; nt < 6; ++nt)
          acc[nt] = __builtin_amdgcn_mfma_f32_16x16x32_bf16(ua.v, Breg[nt][kc], acc[nt], 0, 0, 0);
      }
      // ---- stash partials (C layout: col=lane&15, row=quad*4+r) ----
#pragma unroll
      for (int nt = 0; nt < 6; ++nt)
#pragma unroll
        for (int r = 0; r < 4; ++r)
          Gs[wv][(la16 * 4 + r) * 100 + nt * 16 + la15] = acc[nt][r];
      __syncthreads();
      // ---- reduce 4 wave-partials (float2 per gate) ----
#pragma unroll
      for (int w = 0; w < 4; ++w) {
        const float2 r2 = *(const float2*)&Gs[w][m * 100 + j2];
        const float2 z2 = *(const float2*)&Gs[w][m * 100 + 32 + j2];
        const float2 n2 = *(const float2*)&Gs[w][m * 100 + 64 + j2];
        Gr0 += r2.x; Gr1 += r2.y; Gz0 += z2.x; Gz1 += z2.y; Gn0 += n2.x; Gn1 += n2.y;
      }
      __syncthreads();                                 // Gs reusable next step
    }
    // ---- gate math (2 cols) ----
    const float gr0 = Gr0 + bR.x + giR.x, gr1 = Gr1 + bR.y + giR.y;
    const float gz0 = Gz0 + bZ.x + giZ.x, gz1 = Gz1 + bZ.y + giZ.y;
    const float gh0 = Gn0 + bN.x,         gh1 = Gn1 + bN.y;   // b_hh on n-gate scaled by r
    const float rr0 = 1.0f / (1.0f + __expf(-gr0)), rr1 = 1.0f / (1.0f + __expf(-gr1));
    const float zz0 = 1.0f / (1.0f + __expf(-gz0)), zz1 = 1.0f / (1.0f + __expf(-gz1));
    float tg0 = giN.x + rr0 * gh0, tg1 = giN.y + rr1 * gh1;
    tg0 = fminf(fmaxf(tg0, -15.0f), 15.0f);
    tg1 = fminf(fmaxf(tg1, -15.0f), 15.0f);
    const float e20 = __expf(2.0f * tg0), e21 = __expf(2.0f * tg1);
    const float nn0 = (e20 - 1.0f) / (e20 + 1.0f), nn1 = (e21 - 1.0f) / (e21 + 1.0f);
    h0 = (1.0f - zz0) * nn0 + zz0 * h0;
    h1 = (1.0f - zz1) * nn1 + zz1 * h1;
    if (t < 63) {
      // ---- tagged h store: fire-and-forget, self-validating ----
      u64* const hw = (t & 1) ? wA0 : wA1;
      const u32 hpack = (u32)f2bf(h0) | ((u32)f2bf(h1) << 16);
      __hip_atomic_store(hw, (u64)hpack | ((u64)(u32)(t + 1) << 32),
                         __ATOMIC_RELAXED, __HIP_MEMORY_SCOPE_AGENT);
    }
    // ---- hrbf store + gi prefetch (overlap next step's poll) ----
    const u32 hrpack = (u32)f2bf(fmaxf(h0, 0.0f)) | ((u32)f2bf(fmaxf(h1, 0.0f)) << 16);
    *(u32*)(hrbf + ((size_t)t * 128 + seq) * 1024 + colA) = hrpack;
    if (t < 63) {
      const size_t g = gb0 + (size_t)(t + 1) * 3072;
      giR = *(const float2*)(gi + g);
      giZ = *(const float2*)(gi + g + 1024);
      giN = *(const float2*)(gi + g + 2048);
    }
  }
}

// ---------- host ----------
extern "C" void kernel_launch(void* const* d_in, const int* in_sizes, int n_in,
                              void* d_out, int out_size, void* d_ws, size_t ws_size,
                              hipStream_t stream) {
  const float* feats = (const float*)d_in[0];
  const float* fc_w  = (const float*)d_in[1];
  const float* fc_b  = (const float*)d_in[2];
  const float* cls_w = (const float*)d_in[3];
  const float* cls_b = (const float*)d_in[4];
  const float* w_ih  = (const float*)d_in[5];
  const float* w_hh  = (const float*)d_in[6];
  const float* b_ih  = (const float*)d_in[7];
  const float* b_hh  = (const float*)d_in[8];
  const float* cf_w  = (const float*)d_in[9];
  const float* cf_b  = (const float*)d_in[10];
  const float* mk_w  = (const float*)d_in[11];
  const float* mk_b  = (const float*)d_in[12];

  char* ws = (char*)d_ws;
  size_t off = 0;
  auto alloc = [&](size_t b) { char* p = ws + off; off += (b + 255) & ~(size_t)255; return p; };
  u16*  featsbf = (u16*)alloc((size_t)8192 * 2048 * 2);
  u16*  xbf     = featsbf;                 // alias: feats_bf dead after fc GEMM
  u16*  fcwbf   = (u16*)alloc((size_t)2048 * 2048 * 2);
  u16*  wihbf   = (u16*)alloc((size_t)3072 * 2048 * 2);
  u16*  whhbf   = (u16*)alloc((size_t)3072 * 1024 * 2);
  u16*  clsp    = (u16*)alloc((size_t)32 * 2048 * 2);
  u16*  headp   = (u16*)alloc((size_t)32 * 1024 * 2);
  float* gi     = (float*)alloc((size_t)8192 * 3072 * 4);
  u64*  hbf0    = (u64*)alloc((size_t)128 * 512 * 8);   // tagged {hpack, tag}
  u64*  hbf1    = (u64*)alloc((size_t)128 * 512 * 8);
  u16*  hrbf    = (u16*)alloc((size_t)8192 * 1024 * 2);

  float* out_enc  = (float*)d_out;                       // [8192,22]
  float* out_mask = out_enc + (size_t)8192 * 22;         // [8192,2]
  float* out_x    = out_mask + (size_t)8192 * 2;         // [16,512,2048]
  float* out_vl   = out_x + (size_t)8192 * 2048;         // [16,512,21]

  cvt_bf16<<<16384, 256, 0, stream>>>(feats, featsbf, 4194304);
  cvt_bf16<<<4096, 256, 0, stream>>>(fc_w, fcwbf, 1048576);
  cvt_bf16<<<6144, 256, 0, stream>>>(w_ih, wihbf, 1572864);
  cvt_bf16<<<3072, 256, 0, stream>>>(w_hh, whhbf, 786432);
  pad_cls<<<256, 256, 0, stream>>>(cls_w, clsp);
  pad_head<<<128, 256, 0, stream>>>(cf_w, mk_w, headp);

  // x_pre = relu(feats @ fc_w^T + fc_b) -> out_x (fp32)
  gemm128<1><<<dim3(64, 16), 256, 0, stream>>>(featsbf, fcwbf, fc_b, out_x, 2048, 2048);
  // in-place dropout on out_x; also writes bf16 x into ws
  dropout_kernel<<<16384, 256, 0, stream>>>(out_x, xbf);
  // vl_preds
  gemm_skinny<0><<<128, 256, 0, stream>>>(xbf, clsp, cls_b, nullptr, out_vl, nullptr, 2048);
  // gi = x @ w_ih^T + b_ih   (b_hh NOT folded: n-gate needs r*(gh+b_hh))
  gemm128<0><<<dim3(64, 24), 256, 0, stream>>>(xbf, wihbf, b_ih, gi, 3072, 2048);

  // all 64 GRU steps in one persistent kernel (tagged-data sync, no flags)
  gru_persistent<<<GRU_BLOCKS, 256, 0, stream>>>(whhbf, gi, b_hh, hbf0, hbf1, hrbf);

  // heads: enc_scores + mask_scores
  gemm_skinny<1><<<128, 256, 0, stream>>>(hrbf, headp, cf_b, mk_b, out_enc, out_mask, 1024);
}

// Round 4
// 862.915 us; speedup vs baseline: 7812.9292x; 1.0980x over previous
//
#include <hip/hip_runtime.h>
#include <stdint.h>

using u16 = unsigned short;
using u32 = unsigned int;
using u64 = unsigned long long;

typedef short bf8_t __attribute__((ext_vector_type(8)));   // 8 bf16 values (4 VGPRs)
typedef float f4_t  __attribute__((ext_vector_type(4)));

// ---------- helpers ----------
__device__ __forceinline__ u16 f2bf(float f) {
  u32 u = __float_as_uint(f);
  u32 r = (u + 0x7FFFu + ((u >> 16) & 1u)) >> 16;   // RNE
  return (u16)r;
}

__device__ __forceinline__ void cp16(const void* g, void* l) {
  // async global->LDS, 16B per lane; LDS dest = wave-uniform base + lane*16
  __builtin_amdgcn_global_load_lds(
      (const __attribute__((address_space(1))) u32*)g,
      (__attribute__((address_space(3))) u32*)l, 16, 0, 0);
}

// JAX threefry2x32, key = (0, 42)  [jax.random.key(42)]
__device__ __forceinline__ void threefry_0_42(u32 x0, u32 x1, u32& o0, u32& o1) {
  const u32 k0 = 0u, k1 = 42u;
  const u32 k2 = 0x1BD11BDAu ^ k0 ^ k1;
#define TFR(r) { x0 += x1; x1 = (x1 << r) | (x1 >> (32 - r)); x1 ^= x0; }
  x0 += k0; x1 += k1;
  TFR(13) TFR(15) TFR(26) TFR(6)   x0 += k1; x1 += k2 + 1u;
  TFR(17) TFR(29) TFR(16) TFR(24)  x0 += k2; x1 += k0 + 2u;
  TFR(13) TFR(15) TFR(26) TFR(6)   x0 += k0; x1 += k1 + 3u;
  TFR(17) TFR(29) TFR(16) TFR(24)  x0 += k1; x1 += k2 + 4u;
  TFR(13) TFR(15) TFR(26) TFR(6)   x0 += k2; x1 += k0 + 5u;
#undef TFR
  o0 = x0; o1 = x1;
}

// ---------- conversion / padding ----------
__global__ __launch_bounds__(256)
void cvt_bf16(const float* __restrict__ s, u16* __restrict__ d, int n4) {
  const int i = blockIdx.x * 256 + threadIdx.x;
  if (i >= n4) return;
  const float4 v = ((const float4*)s)[i];
  ushort4 o;
  o.x = f2bf(v.x); o.y = f2bf(v.y); o.z = f2bf(v.z); o.w = f2bf(v.w);
  ((ushort4*)d)[i] = o;
}

__global__ __launch_bounds__(256)
void pad_cls(const float* __restrict__ src, u16* __restrict__ dst) {
  const int i = blockIdx.x * 256 + threadIdx.x;      // 32*2048
  const int row = i >> 11, col = i & 2047;
  dst[i] = (row < 21) ? f2bf(src[row * 2048 + col]) : (u16)0;
}

__global__ __launch_bounds__(256)
void pad_head(const float* __restrict__ cf, const float* __restrict__ mk,
              u16* __restrict__ dst) {
  const int i = blockIdx.x * 256 + threadIdx.x;      // 32*1024
  const int row = i >> 10, col = i & 1023;
  float v = 0.0f;
  if (row < 22)      v = cf[row * 1024 + col];
  else if (row < 24) v = mk[(row - 22) * 1024 + col];
  dst[i] = f2bf(v);
}

// ---------- big GEMM: C[M,N] = A[M,K] * B[N,K]^T (+bias, opt relu) ----------
// 128x128 tile, BK=64, 256 threads (4 waves as 2x2 of 64x64)
template<int RELU>
__global__ __launch_bounds__(256)
void gemm128(const u16* __restrict__ A, const u16* __restrict__ Bw,
             const float* __restrict__ bias, float* __restrict__ C,
             int N, int K) {
  __shared__ __align__(16) u16 As[128 * 64];
  __shared__ __align__(16) u16 Bs[128 * 64];
  const int tid = threadIdx.x;
  const int wv = tid >> 6, lane = tid & 63;
  const int wm = wv >> 1, wn = wv & 1;
  const u16* Ab = A + (size_t)blockIdx.x * 128 * K;
  const u16* Bb = Bw + (size_t)blockIdx.y * 128 * K;
  const int lr = lane >> 3, lc = lane & 7;
  f4_t acc[4][4] = {};
  for (int k0 = 0; k0 < K; k0 += 64) {
#pragma unroll
    for (int i = 0; i < 4; ++i) {
      const int row = wv * 32 + i * 8;
      cp16(Ab + (size_t)(row + lr) * K + (k0 + lc * 8), &As[row * 64]);
      cp16(Bb + (size_t)(row + lr) * K + (k0 + lc * 8), &Bs[row * 64]);
    }
    __syncthreads();
#pragma unroll
    for (int kk = 0; kk < 2; ++kk) {
      bf8_t av[4], bv[4];
#pragma unroll
      for (int mt = 0; mt < 4; ++mt)
        av[mt] = *(const bf8_t*)&As[(wm * 64 + mt * 16 + (lane & 15)) * 64 + kk * 32 + (lane >> 4) * 8];
#pragma unroll
      for (int nt = 0; nt < 4; ++nt)
        bv[nt] = *(const bf8_t*)&Bs[(wn * 64 + nt * 16 + (lane & 15)) * 64 + kk * 32 + (lane >> 4) * 8];
#pragma unroll
      for (int mt = 0; mt < 4; ++mt)
#pragma unroll
        for (int nt = 0; nt < 4; ++nt)
          acc[mt][nt] = __builtin_amdgcn_mfma_f32_16x16x32_bf16(av[mt], bv[nt], acc[mt][nt], 0, 0, 0);
    }
    __syncthreads();
  }
  const int q = lane >> 4, cn = lane & 15;
#pragma unroll
  for (int mt = 0; mt < 4; ++mt) {
#pragma unroll
    for (int nt = 0; nt < 4; ++nt) {
      const int col = blockIdx.y * 128 + wn * 64 + nt * 16 + cn;
      const float bb = bias[col];
#pragma unroll
      for (int r = 0; r < 4; ++r) {
        const int row = blockIdx.x * 128 + wm * 64 + mt * 16 + q * 4 + r;
        float v = acc[mt][nt][r] + bb;
        if (RELU) v = fmaxf(v, 0.0f);
        C[(size_t)row * N + col] = v;
      }
    }
  }
}

// ---------- skinny GEMM: C[M,32] = A[M,K] * B[32,K]^T, M-tile 64 ----------
// HEAD=0: vl_preds (cols<21, +cls_b). HEAD=1: enc (cols<22,+cf_b) / mask (cols 22..23,+mk_b)
template<int HEAD>
__global__ __launch_bounds__(256)
void gemm_skinny(const u16* __restrict__ A, const u16* __restrict__ Bw,
                 const float* __restrict__ bias, const float* __restrict__ bias2,
                 float* __restrict__ C0, float* __restrict__ C1, int K) {
  __shared__ __align__(16) u16 As[64 * 64];
  __shared__ __align__(16) u16 Bs[32 * 64];
  const int tid = threadIdx.x, wv = tid >> 6, lane = tid & 63;
  const u16* Ab = A + (size_t)blockIdx.x * 64 * K;
  const int lr = lane >> 3, lc = lane & 7;
  f4_t acc[2] = {};
  for (int k0 = 0; k0 < K; k0 += 64) {
#pragma unroll
    for (int i = 0; i < 2; ++i) {
      const int row = wv * 16 + i * 8;
      cp16(Ab + (size_t)(row + lr) * K + (k0 + lc * 8), &As[row * 64]);
    }
    {
      const int row = wv * 8;
      cp16(Bw + (size_t)(row + lr) * K + (k0 + lc * 8), &Bs[row * 64]);
    }
    __syncthreads();
#pragma unroll
    for (int kk = 0; kk < 2; ++kk) {
      bf8_t a = *(const bf8_t*)&As[(wv * 16 + (lane & 15)) * 64 + kk * 32 + (lane >> 4) * 8];
#pragma unroll
      for (int nt = 0; nt < 2; ++nt) {
        bf8_t b = *(const bf8_t*)&Bs[(nt * 16 + (lane & 15)) * 64 + kk * 32 + (lane >> 4) * 8];
        acc[nt] = __builtin_amdgcn_mfma_f32_16x16x32_bf16(a, b, acc[nt], 0, 0, 0);
      }
    }
    __syncthreads();
  }
  const int q = lane >> 4, cn = lane & 15;
#pragma unroll
  for (int nt = 0; nt < 2; ++nt) {
    const int col = nt * 16 + cn;
#pragma unroll
    for (int r = 0; r < 4; ++r) {
      const int row = blockIdx.x * 64 + wv * 16 + q * 4 + r;
      const float v = acc[nt][r];
      if (HEAD) {
        if (col < 22)      C0[(size_t)row * 22 + col] = v + bias[col];
        else if (col < 24) C1[(size_t)row * 2 + (col - 22)] = v + bias2[col - 22];
      } else {
        if (col < 21)      C0[(size_t)row * 21 + col] = v + bias[col];
      }
    }
  }
}

// ---------- dropout: JAX partitionable threefry bernoulli, key 42, p_keep=0.7 ----------
__global__ __launch_bounds__(256)
void dropout_kernel(float* __restrict__ x, u16* __restrict__ xbf) {
  const u32 tid = blockIdx.x * 256u + threadIdx.x;   // 2^22 threads
  const u32 j0 = tid * 4u;
  float4 a = *(const float4*)(x + j0);
  float av[4] = {a.x, a.y, a.z, a.w};
  u16 abf[4];
#pragma unroll
  for (int i = 0; i < 4; ++i) {
    u32 o0, o1;
    threefry_0_42(0u, j0 + (u32)i, o0, o1);
    const u32 bits = o0 ^ o1;
    const float u1 = __uint_as_float((bits >> 9) | 0x3f800000u) - 1.0f;
    av[i] = (u1 < 0.7f) ? av[i] * (1.0f / 0.7f) : 0.0f;
    abf[i] = f2bf(av[i]);
  }
  float4 oa; oa.x = av[0]; oa.y = av[1]; oa.z = av[2]; oa.w = av[3];
  *(float4*)(x + j0) = oa;
  ushort4 ua; ua.x = abf[0]; ua.y = abf[1]; ua.z = abf[2]; ua.w = abf[3];
  *(ushort4*)(xbf + j0) = ua;
}

// ---------- persistent GRU v6: tagged sync + REGISTER-RESIDENT weights ----------
// v5 post-mortem: VGPR_Count=160 < 192 proved the compiler sank the Breg loads
// into the t-loop (const __restrict lets it), re-streaming 192KB/block/step =
// 3.1GB of LLC traffic -> THAT was the regression, not the sync. v6 fixes:
// (1) Breg loaded via asm volatile global_load_dwordx4 -- cannot be
//     rematerialized/sunk, forcing 192 VGPRs of weights to stay resident.
// (2) poll per 4-u64 chunk (8 VGPRs live, not 64) with s_sleep(2) backoff,
//     MFMA each chunk as it validates -- 16x less poll traffic, and the
//     register peak (192 Breg + 8 chunk + acc) fits the 256-VGPR file.
// Geometry/protocol unchanged from v5 (passed): 8 grp x 16 seq, 32 cb x 32
// cols; h as u64 {2xbf16, tag=t+1} agent-scope RELAXED; fire-and-forget
// writes; two-buffer parity race-free; 0xAA poison never matches tags 1..63.
#define GRU_BLOCKS 256
__global__ __launch_bounds__(256, 1)
void gru_persistent(const u16* __restrict__ whh, const float* __restrict__ gi,
                    const float* __restrict__ bhh, u64* __restrict__ hbuf0,
                    u64* __restrict__ hbuf1, u16* __restrict__ hrbf) {
  __shared__ __align__(16) float Gs[4][16 * 100];     // 25.6 KB wave-partial G
  __shared__ __align__(16) u32 ldspad[14848];         // pad -> 85 KB => 1 block/CU
  asm volatile("" :: "v"((u32)(size_t)(void*)ldspad) : "memory");  // keep pad live

  const int tid = threadIdx.x, wv = tid >> 6, lane = tid & 63;
  const int la15 = lane & 15, la16 = lane >> 4;
  const int slot = blockIdx.x & 31, grp = blockIdx.x >> 5;
  const int col0 = slot * 32;                          // 32 hid cols per block
  const int seq0 = grp * 16;                           // 16 seqs per group

  // ---- whh slab -> REGISTERS (asm volatile: not sinkable): 96 rows x K=256 ----
  const int kb = wv * 256 + la16 * 8;                  // this wave's K slice base
  bf8_t Breg[6][8];                                    // 192 VGPRs, loop-invariant
#pragma unroll
  for (int nt = 0; nt < 6; ++nt) {
    const size_t grow = (size_t)((nt >> 1) * 1024 + col0 + (nt & 1) * 16 + la15);
#pragma unroll
    for (int kc = 0; kc < 8; ++kc) {
      const u16* p = &whh[grow * 1024 + kb + kc * 32];
      asm volatile("global_load_dwordx4 %0, %1, off" : "=v"(Breg[nt][kc]) : "v"(p));
    }
  }
  asm volatile("s_waitcnt vmcnt(0)" ::: "memory");

  // ---- per-thread persistent state: 1 seq x 2 adjacent cols ----
  const int j2 = (tid & 15) * 2;                       // even col within 32-tile
  const int m = tid >> 4;                              // seq within group (0..15)
  const int colA = col0 + j2;
  const int seq = seq0 + m;
  float h0 = 0.0f, h1 = 0.0f;                          // fp32 h master copy (regs)
  const float2 bR = *(const float2*)(bhh + colA);
  const float2 bZ = *(const float2*)(bhh + 1024 + colA);
  const float2 bN = *(const float2*)(bhh + 2048 + colA);
  const size_t gb0 = ((size_t)((seq >> 3) * 512 + (seq & 7) * 64)) * 3072 + colA;
  float2 giR = *(const float2*)(gi + gb0);
  float2 giZ = *(const float2*)(gi + gb0 + 1024);
  float2 giN = *(const float2*)(gi + gb0 + 2048);

  // reader fragment base (u64 units; row seq0+la15, this wave's K slice)
  const size_t rbase = (size_t)(seq0 + la15) * 512 + (size_t)(wv * 128 + la16 * 4);
  u64* const rA0 = hbuf0 + rbase;
  u64* const rA1 = hbuf1 + rbase;
  // writer address (u64 units)
  u64* const wA0 = hbuf0 + (size_t)seq * 512 + (colA >> 1);
  u64* const wA1 = hbuf1 + (size_t)seq * 512 + (colA >> 1);

  for (int t = 0; t < 64; ++t) {
    float Gr0 = 0.f, Gr1 = 0.f, Gz0 = 0.f, Gz1 = 0.f, Gn0 = 0.f, Gn1 = 0.f;
    if (t > 0) {
      u64* const rb = (t & 1) ? rA1 : rA0;             // buffer written at t-1
      const u32 target = (u32)t;
      f4_t acc[6] = {};
      // ---- per-chunk: poll 4 tagged u64s until valid, then MFMA that chunk ----
#pragma unroll
      for (int kc = 0; kc < 8; ++kc) {
        u64 q0, q1, q2, q3;
        int guard = 0;
        while (true) {
          q0 = __hip_atomic_load(rb + kc * 16 + 0, __ATOMIC_RELAXED, __HIP_MEMORY_SCOPE_AGENT);
          q1 = __hip_atomic_load(rb + kc * 16 + 1, __ATOMIC_RELAXED, __HIP_MEMORY_SCOPE_AGENT);
          q2 = __hip_atomic_load(rb + kc * 16 + 2, __ATOMIC_RELAXED, __HIP_MEMORY_SCOPE_AGENT);
          q3 = __hip_atomic_load(rb + kc * 16 + 3, __ATOMIC_RELAXED, __HIP_MEMORY_SCOPE_AGENT);
          const bool ok = ((u32)(q0 >> 32) == target) & ((u32)(q1 >> 32) == target) &
                          ((u32)(q2 >> 32) == target) & ((u32)(q3 >> 32) == target);
          if (__ballot(ok) == ~0ull) break;
          if (++guard > 50000) break;                  // fail-fast, never hang
          __builtin_amdgcn_s_sleep(2);                 // backoff: cut LLC poll traffic
        }
        union { bf8_t v; u32 d[4]; } ua;
        ua.d[0] = (u32)q0; ua.d[1] = (u32)q1; ua.d[2] = (u32)q2; ua.d[3] = (u32)q3;
#pragma unroll
        for (int nt = 0; nt < 6; ++nt)
          acc[nt] = __builtin_amdgcn_mfma_f32_16x16x32_bf16(ua.v, Breg[nt][kc], acc[nt], 0, 0, 0);
      }
      // ---- stash partials (C layout: col=lane&15, row=quad*4+r) ----
#pragma unroll
      for (int nt = 0; nt < 6; ++nt)
#pragma unroll
        for (int r = 0; r < 4; ++r)
          Gs[wv][(la16 * 4 + r) * 100 + nt * 16 + la15] = acc[nt][r];
      __syncthreads();
      // ---- reduce 4 wave-partials (float2 per gate) ----
#pragma unroll
      for (int w = 0; w < 4; ++w) {
        const float2 r2 = *(const float2*)&Gs[w][m * 100 + j2];
        const float2 z2 = *(const float2*)&Gs[w][m * 100 + 32 + j2];
        const float2 n2 = *(const float2*)&Gs[w][m * 100 + 64 + j2];
        Gr0 += r2.x; Gr1 += r2.y; Gz0 += z2.x; Gz1 += z2.y; Gn0 += n2.x; Gn1 += n2.y;
      }
      __syncthreads();                                 // Gs reusable next step
    }
    // ---- gate math (2 cols) ----
    const float gr0 = Gr0 + bR.x + giR.x, gr1 = Gr1 + bR.y + giR.y;
    const float gz0 = Gz0 + bZ.x + giZ.x, gz1 = Gz1 + bZ.y + giZ.y;
    const float gh0 = Gn0 + bN.x,         gh1 = Gn1 + bN.y;   // b_hh on n-gate scaled by r
    const float rr0 = 1.0f / (1.0f + __expf(-gr0)), rr1 = 1.0f / (1.0f + __expf(-gr1));
    const float zz0 = 1.0f / (1.0f + __expf(-gz0)), zz1 = 1.0f / (1.0f + __expf(-gz1));
    float tg0 = giN.x + rr0 * gh0, tg1 = giN.y + rr1 * gh1;
    tg0 = fminf(fmaxf(tg0, -15.0f), 15.0f);
    tg1 = fminf(fmaxf(tg1, -15.0f), 15.0f);
    const float e20 = __expf(2.0f * tg0), e21 = __expf(2.0f * tg1);
    const float nn0 = (e20 - 1.0f) / (e20 + 1.0f), nn1 = (e21 - 1.0f) / (e21 + 1.0f);
    h0 = (1.0f - zz0) * nn0 + zz0 * h0;
    h1 = (1.0f - zz1) * nn1 + zz1 * h1;
    if (t < 63) {
      // ---- tagged h store: fire-and-forget, self-validating ----
      u64* const hw = (t & 1) ? wA0 : wA1;
      const u32 hpack = (u32)f2bf(h0) | ((u32)f2bf(h1) << 16);
      __hip_atomic_store(hw, (u64)hpack | ((u64)(u32)(t + 1) << 32),
                         __ATOMIC_RELAXED, __HIP_MEMORY_SCOPE_AGENT);
    }
    // ---- hrbf store + gi prefetch (overlap next step's poll) ----
    const u32 hrpack = (u32)f2bf(fmaxf(h0, 0.0f)) | ((u32)f2bf(fmaxf(h1, 0.0f)) << 16);
    *(u32*)(hrbf + ((size_t)t * 128 + seq) * 1024 + colA) = hrpack;
    if (t < 63) {
      const size_t g = gb0 + (size_t)(t + 1) * 3072;
      giR = *(const float2*)(gi + g);
      giZ = *(const float2*)(gi + g + 1024);
      giN = *(const float2*)(gi + g + 2048);
    }
  }
}

// ---------- host ----------
extern "C" void kernel_launch(void* const* d_in, const int* in_sizes, int n_in,
                              void* d_out, int out_size, void* d_ws, size_t ws_size,
                              hipStream_t stream) {
  const float* feats = (const float*)d_in[0];
  const float* fc_w  = (const float*)d_in[1];
  const float* fc_b  = (const float*)d_in[2];
  const float* cls_w = (const float*)d_in[3];
  const float* cls_b = (const float*)d_in[4];
  const float* w_ih  = (const float*)d_in[5];
  const float* w_hh  = (const float*)d_in[6];
  const float* b_ih  = (const float*)d_in[7];
  const float* b_hh  = (const float*)d_in[8];
  const float* cf_w  = (const float*)d_in[9];
  const float* cf_b  = (const float*)d_in[10];
  const float* mk_w  = (const float*)d_in[11];
  const float* mk_b  = (const float*)d_in[12];

  char* ws = (char*)d_ws;
  size_t off = 0;
  auto alloc = [&](size_t b) { char* p = ws + off; off += (b + 255) & ~(size_t)255; return p; };
  u16*  featsbf = (u16*)alloc((size_t)8192 * 2048 * 2);
  u16*  xbf     = featsbf;                 // alias: feats_bf dead after fc GEMM
  u16*  fcwbf   = (u16*)alloc((size_t)2048 * 2048 * 2);
  u16*  wihbf   = (u16*)alloc((size_t)3072 * 2048 * 2);
  u16*  whhbf   = (u16*)alloc((size_t)3072 * 1024 * 2);
  u16*  clsp    = (u16*)alloc((size_t)32 * 2048 * 2);
  u16*  headp   = (u16*)alloc((size_t)32 * 1024 * 2);
  float* gi     = (float*)alloc((size_t)8192 * 3072 * 4);
  u64*  hbf0    = (u64*)alloc((size_t)128 * 512 * 8);   // tagged {hpack, tag}
  u64*  hbf1    = (u64*)alloc((size_t)128 * 512 * 8);
  u16*  hrbf    = (u16*)alloc((size_t)8192 * 1024 * 2);

  float* out_enc  = (float*)d_out;                       // [8192,22]
  float* out_mask = out_enc + (size_t)8192 * 22;         // [8192,2]
  float* out_x    = out_mask + (size_t)8192 * 2;         // [16,512,2048]
  float* out_vl   = out_x + (size_t)8192 * 2048;         // [16,512,21]

  cvt_bf16<<<16384, 256, 0, stream>>>(feats, featsbf, 4194304);
  cvt_bf16<<<4096, 256, 0, stream>>>(fc_w, fcwbf, 1048576);
  cvt_bf16<<<6144, 256, 0, stream>>>(w_ih, wihbf, 1572864);
  cvt_bf16<<<3072, 256, 0, stream>>>(w_hh, whhbf, 786432);
  pad_cls<<<256, 256, 0, stream>>>(cls_w, clsp);
  pad_head<<<128, 256, 0, stream>>>(cf_w, mk_w, headp);

  // x_pre = relu(feats @ fc_w^T + fc_b) -> out_x (fp32)
  gemm128<1><<<dim3(64, 16), 256, 0, stream>>>(featsbf, fcwbf, fc_b, out_x, 2048, 2048);
  // in-place dropout on out_x; also writes bf16 x into ws
  dropout_kernel<<<16384, 256, 0, stream>>>(out_x, xbf);
  // vl_preds
  gemm_skinny<0><<<128, 256, 0, stream>>>(xbf, clsp, cls_b, nullptr, out_vl, nullptr, 2048);
  // gi = x @ w_ih^T + b_ih   (b_hh NOT folded: n-gate needs r*(gh+b_hh))
  gemm128<0><<<dim3(64, 24), 256, 0, stream>>>(xbf, wihbf, b_ih, gi, 3072, 2048);

  // all 64 GRU steps in one persistent kernel (tagged-data sync, no flags)
  gru_persistent<<<GRU_BLOCKS, 256, 0, stream>>>(whhbf, gi, b_hh, hbf0, hbf1, hrbf);

  // heads: enc_scores + mask_scores
  gemm_skinny<1><<<128, 256, 0, stream>>>(hrbf, headp, cf_b, mk_b, out_enc, out_mask, 1024);
}